// Round 7
// baseline (145.523 us; speedup 1.0000x reference)
//
#include <hip/hip_runtime.h>
#include <math.h>

#define B 16
#define E 64
#define H 8
#define L 2048
#define M 64
#define PLANE (B*H*E*M)   // 524288 float2 per spectral plane

typedef _Float16 f16x8 __attribute__((ext_vector_type(8)));
typedef _Float16 f16x4 __attribute__((ext_vector_type(4)));
typedef float    f32x4 __attribute__((ext_vector_type(4)));

#define MFMA16(a, b, c) __builtin_amdgcn_mfma_f32_16x16x32_f16((a), (b), (c), 0, 0, 0)

// exact 32-pt DFT twiddles: CS32[j]=cos(pi j/16), SN32[j]=sin(pi j/16)
constexpr float CS32[32] = {
     1.0f,                    0.9807852804032304f,   0.9238795325112868f,   0.8314696123025452f,
     0.7071067811865476f,     0.5555702330196022f,   0.3826834323650898f,   0.1950903220161283f,
     0.0f,                   -0.1950903220161283f,  -0.3826834323650898f,  -0.5555702330196022f,
    -0.7071067811865476f,    -0.8314696123025452f,  -0.9238795325112868f,  -0.9807852804032304f,
    -1.0f,                   -0.9807852804032304f,  -0.9238795325112868f,  -0.8314696123025452f,
    -0.7071067811865476f,    -0.5555702330196022f,  -0.3826834323650898f,  -0.1950903220161283f,
     0.0f,                    0.1950903220161283f,   0.3826834323650898f,   0.5555702330196022f,
     0.7071067811865476f,     0.8314696123025452f,   0.9238795325112868f,   0.9807852804032304f
};
constexpr float SN32[32] = {
     0.0f,                    0.1950903220161283f,   0.3826834323650898f,   0.5555702330196022f,
     0.7071067811865476f,     0.8314696123025452f,   0.9238795325112868f,   0.9807852804032304f,
     1.0f,                    0.9807852804032304f,   0.9238795325112868f,   0.8314696123025452f,
     0.7071067811865476f,     0.5555702330196022f,   0.3826834323650898f,   0.1950903220161283f,
     0.0f,                   -0.1950903220161283f,  -0.3826834323650898f,  -0.5555702330196022f,
    -0.7071067811865476f,    -0.8314696123025452f,  -0.9238795325112868f,  -0.9807852804032304f,
    -1.0f,                   -0.9807852804032304f,  -0.9238795325112868f,  -0.8314696123025452f,
    -0.7071067811865476f,    -0.5555702330196022f,  -0.3826834323650898f,  -0.1950903220161283f
};

__device__ inline void ctanhf_stable(float x, float y, float& re, float& im) {
    float ax = fabsf(x);
    if (ax > 11.0f) { re = copysignf(1.0f, x); im = 0.0f; return; }
    float t    = tanf(y);
    float beta = 1.0f + t * t;
    float s    = sinhf(x);
    float rho  = sqrtf(1.0f + s * s);
    float den  = 1.0f + beta * s * s;
    re = (beta * rho * s) / den;
    im = t / den;
}

// ---------------------------------------------------------------------------
// DFT matrix as split-fp16: Bg[n][k], n=2m -> cos(2pi m k/L), n=2m+1 -> -sin.
// hi = fp16(v), lo = fp16(v - hi). f64-exact angles (one-time, ~262K threads).
// ---------------------------------------------------------------------------
__global__ __launch_bounds__(256) void k_dftmat(_Float16* __restrict__ Bhi,
                                                _Float16* __restrict__ Blo)
{
    int idx = blockIdx.x * 256 + threadIdx.x;   // 0..262143 = 128n x 2048k
    int n = idx >> 11, kk = idx & 2047;
    int m = n >> 1;
    double a = 6.2831853071795864769252867665590058 * (double)(m * kk) / 2048.0;
    double v = (n & 1) ? -sin(a) : cos(a);
    _Float16 h = (_Float16)v;
    Bhi[idx] = h;
    Blo[idx] = (_Float16)(float)(v - (double)h);
}

// ---------------------------------------------------------------------------
// W transpose: w_re/w_im [H][E][O][M] -> Wt float2 [H][m][E][O].
// ---------------------------------------------------------------------------
__global__ __launch_bounds__(256) void k_wtrans(const float* __restrict__ wre,
                                                const float* __restrict__ wim,
                                                float2* __restrict__ Wt)
{
    __shared__ float tre[64][65], tim[64][65];
    int h  = blockIdx.x >> 6, rt = blockIdx.x & 63;
    int tid = threadIdx.x;

    int x = tid & 63, r4 = tid >> 6;
    const size_t base = ((size_t)h * 4096 + (size_t)rt * 64) * 64;
    #pragma unroll
    for (int j = 0; j < 16; ++j) {
        int row = j * 4 + r4;
        tre[row][x] = wre[base + (size_t)row * 64 + x];
        tim[row][x] = wim[base + (size_t)row * 64 + x];
    }
    __syncthreads();

    int row = tid & 63, x4 = tid >> 6;
    #pragma unroll
    for (int j = 0; j < 16; ++j) {
        int xx = j * 4 + x4;
        Wt[((size_t)h * 64 + xx) * 4096 + (size_t)rt * 64 + row] =
            make_float2(tre[row][xx], tim[row][xx]);
    }
}

// ---------------------------------------------------------------------------
// MFMA forward DFT: X[row][n] = sum_k x[row][k] * Bmat[k][n]  (N=128 = 64
// modes interleaved re/im). Split-fp16: x=ah+al, B=bh+bl, 3 MFMA products.
// M-tile 32 rows (grid 512), 4 waves, wave w owns rows[0..32) x cols[32w..+32).
// A staged in LDS (XOR-swizzled hi/lo, K-chunk 64, reg prefetch); B from L2.
// ---------------------------------------------------------------------------
__global__ __launch_bounds__(256) void k_dftg(const float* __restrict__ q,
                                              const float* __restrict__ kt,
                                              const _Float16* __restrict__ Bhi,
                                              const _Float16* __restrict__ Blo,
                                              float* __restrict__ Xq,
                                              float* __restrict__ Xk)
{
    __shared__ _Float16 Ah[32][64], Al[32][64];

    int t = threadIdx.x;
    int l = t & 63;
    int w = t >> 6;            // wave 0..3
    int l15 = l & 15, g = l >> 4;

    // staging map: thread -> (row, 8-col group), XOR-swizzled column group
    int srow  = t >> 3;
    int sgrp  = ((t & 7) ^ (srow & 7)) * 8;      // swizzled col base
    int grow_s = blockIdx.x * 32 + srow;
    const float* srcP = (grow_s >= 8192 ? kt + (size_t)(grow_s - 8192) * 2048
                                        : q  + (size_t)grow_s * 2048) + (t & 7) * 8;

    float4 st0 = *(const float4*)(srcP);
    float4 st1 = *(const float4*)(srcP + 4);

    // B pointers: Bg[n][k] row n = w*32 + nf*16 + l15, k-phase g*8
    const size_t boff = (size_t)(w * 32 + l15) * 2048 + (size_t)g * 8;
    const _Float16* bh0 = Bhi + boff;
    const _Float16* bh1 = Bhi + boff + (size_t)16 * 2048;
    const _Float16* bl0 = Blo + boff;
    const _Float16* bl1 = Blo + boff + (size_t)16 * 2048;

    f32x4 acc00 = {0.f,0.f,0.f,0.f}, acc01 = {0.f,0.f,0.f,0.f};
    f32x4 acc10 = {0.f,0.f,0.f,0.f}, acc11 = {0.f,0.f,0.f,0.f};

    for (int c = 0; c < 32; ++c) {
        __syncthreads();
        // convert staged regs -> LDS hi/lo
        {
            float v0[4] = {st0.x, st0.y, st0.z, st0.w};
            float v1[4] = {st1.x, st1.y, st1.z, st1.w};
            f16x4 h0, l0, h1, l1;
            #pragma unroll
            for (int j = 0; j < 4; ++j) {
                _Float16 a = (_Float16)v0[j];
                h0[j] = a; l0[j] = (_Float16)(v0[j] - (float)a);
                _Float16 b2 = (_Float16)v1[j];
                h1[j] = b2; l1[j] = (_Float16)(v1[j] - (float)b2);
            }
            *(f16x4*)&Ah[srow][sgrp]     = h0;
            *(f16x4*)&Ah[srow][sgrp + 4] = h1;
            *(f16x4*)&Al[srow][sgrp]     = l0;
            *(f16x4*)&Al[srow][sgrp + 4] = l1;
        }
        if (c < 31) {   // prefetch next chunk under compute
            st0 = *(const float4*)(srcP + (c + 1) * 64);
            st1 = *(const float4*)(srcP + (c + 1) * 64 + 4);
        }
        __syncthreads();

        #pragma unroll
        for (int ks = 0; ks < 2; ++ks) {
            int csw = (ks * 32 + g * 8) ^ ((l15 & 7) * 8);
            f16x8 ah0 = *(const f16x8*)&Ah[l15][csw];
            f16x8 ah1 = *(const f16x8*)&Ah[16 + l15][csw];
            f16x8 al0 = *(const f16x8*)&Al[l15][csw];
            f16x8 al1 = *(const f16x8*)&Al[16 + l15][csw];
            int go = c * 64 + ks * 32;
            f16x8 b0h = *(const f16x8*)(bh0 + go);
            f16x8 b1h = *(const f16x8*)(bh1 + go);
            f16x8 b0l = *(const f16x8*)(bl0 + go);
            f16x8 b1l = *(const f16x8*)(bl1 + go);

            acc00 = MFMA16(ah0, b0h, acc00);
            acc01 = MFMA16(ah0, b1h, acc01);
            acc10 = MFMA16(ah1, b0h, acc10);
            acc11 = MFMA16(ah1, b1h, acc11);
            acc00 = MFMA16(ah0, b0l, acc00);
            acc01 = MFMA16(ah0, b1l, acc01);
            acc10 = MFMA16(ah1, b0l, acc10);
            acc11 = MFMA16(ah1, b1l, acc11);
            acc00 = MFMA16(al0, b0h, acc00);
            acc01 = MFMA16(al0, b1h, acc01);
            acc10 = MFMA16(al1, b0h, acc10);
            acc11 = MFMA16(al1, b1h, acc11);
        }
    }

    // write out: C layout col=lane&15, row=(lane>>4)*4+reg (m89-verified)
    #pragma unroll
    for (int mf = 0; mf < 2; ++mf) {
        #pragma unroll
        for (int r = 0; r < 4; ++r) {
            int grow = blockIdx.x * 32 + mf * 16 + g * 4 + r;
            int r13  = grow & 8191;
            int bb = r13 >> 9, e = (r13 >> 3) & 63, hh = r13 & 7;
            float* dst = (grow >= 8192 ? Xk : Xq)
                       + ((size_t)((bb * 8 + hh) * 64 + e)) * 128 + w * 32 + l15;
            f32x4 a0 = mf ? acc10 : acc00;
            f32x4 a1 = mf ? acc11 : acc01;
            dst[0]  = a0[r];
            dst[16] = a1[r];
        }
    }
}

// ---------------------------------------------------------------------------
// Per (bh, x-half): S = tanh(Q^T K) (f64 accum), then
// U[h][x][b][e] = sum_y S[x][y] K[e][y]
// ---------------------------------------------------------------------------
__global__ __launch_bounds__(256) void k_mid(const float2* __restrict__ Xq,
                                             const float2* __restrict__ Xk,
                                             float2* __restrict__ U)
{
    __shared__ float Qre[64][32], Qim[64][32];   // [e][xl]; becomes S [y][xl]
    __shared__ float Kre[64][65], Kim[64][65];   // [e][m], padded

    int bh = blockIdx.x >> 1;
    int xh = (blockIdx.x & 1) * 32;
    int b  = bh >> 3, h = bh & 7;
    int tid = threadIdx.x;
    const float2* xq = Xq + (size_t)bh * 4096;
    const float2* xk = Xk + (size_t)bh * 4096;

    #pragma unroll
    for (int j = 0; j < 8; ++j) {
        int idx = tid + 256 * j;
        int e = idx >> 5, xl = idx & 31;
        float2 v = xq[(e << 6) + xh + xl];
        Qre[e][xl] = v.x; Qim[e][xl] = v.y;
    }
    #pragma unroll
    for (int j = 0; j < 16; ++j) {
        int idx = tid + 256 * j;
        int e = idx >> 6, mm = idx & 63;
        float2 v = xk[idx];
        Kre[e][mm] = v.x; Kim[e][mm] = v.y;
    }
    __syncthreads();

    int x  = tid & 31;
    int y0 = (tid >> 5) * 8;
    double ar[8], ai[8];
    #pragma unroll
    for (int j = 0; j < 8; ++j) { ar[j] = 0.0; ai[j] = 0.0; }

    for (int e = 0; e < 64; ++e) {
        double qr = (double)Qre[e][x], qi = (double)Qim[e][x];
        #pragma unroll
        for (int j = 0; j < 8; ++j) {
            double kr = (double)Kre[e][y0 + j], ki = (double)Kim[e][y0 + j];
            ar[j] += qr * kr - qi * ki;
            ai[j] += qr * ki + qi * kr;
        }
    }
    float trj[8], tij[8];
    #pragma unroll
    for (int j = 0; j < 8; ++j) ctanhf_stable((float)ar[j], (float)ai[j], trj[j], tij[j]);

    __syncthreads();
    #pragma unroll
    for (int j = 0; j < 8; ++j) { Qre[y0 + j][x] = trj[j]; Qim[y0 + j][x] = tij[j]; }
    __syncthreads();

    int eL  = tid & 63;
    int xq4 = tid >> 6;
    float ur[8], ui[8];
    #pragma unroll
    for (int j = 0; j < 8; ++j) { ur[j] = 0.f; ui[j] = 0.f; }

    for (int y = 0; y < 64; ++y) {
        float kr = Kre[eL][y], ki = Kim[eL][y];
        #pragma unroll
        for (int xp = 0; xp < 8; ++xp) {
            int xx = xp * 4 + xq4;
            float sr = Qre[y][xx], si = Qim[y][xx];
            ur[xp] += sr * kr - si * ki;
            ui[xp] += sr * ki + si * kr;
        }
    }
    #pragma unroll
    for (int xp = 0; xp < 8; ++xp) {
        int xx = xp * 4 + xq4;
        U[(((size_t)h * 64 + xh + xx) * 16 + b) * 64 + eL] = make_float2(ur[xp], ui[xp]);
    }
}

// ---------------------------------------------------------------------------
// Per (h, mode x): R[b][o] = sum_e U[b][e] * Wt[e][o]
// ---------------------------------------------------------------------------
__global__ __launch_bounds__(256) void k_wmix(const float2* __restrict__ U,   // [h][x][b][e]
                                              const float2* __restrict__ Wt,  // [h][x][e][o]
                                              float2* __restrict__ R)
{
    __shared__ float2 Usm[16][64];
    __shared__ float2 Wsm[64][64];

    int h = blockIdx.x >> 6, x = blockIdx.x & 63;
    int tid = threadIdx.x;

    const float2* usrc = U  + ((size_t)h * 64 + x) * 1024;
    #pragma unroll
    for (int j = 0; j < 4; ++j) {
        int idx = tid + 256 * j;
        ((float2*)Usm)[idx] = usrc[idx];
    }
    const float2* wsrc = Wt + ((size_t)h * 64 + x) * 4096;
    #pragma unroll
    for (int j = 0; j < 16; ++j) {
        int idx = tid + 256 * j;
        ((float2*)Wsm)[idx] = wsrc[idx];
    }
    __syncthreads();

    int o = tid & 63, b0 = tid >> 6;
    float rr[4], ri[4];
    #pragma unroll
    for (int j = 0; j < 4; ++j) { rr[j] = 0.f; ri[j] = 0.f; }

    for (int e = 0; e < 64; ++e) {
        float2 w = Wsm[e][o];
        #pragma unroll
        for (int j = 0; j < 4; ++j) {
            float2 u = Usm[b0 + 4 * j][e];
            rr[j] += u.x * w.x - u.y * w.y;
            ri[j] += u.x * w.y + u.y * w.x;
        }
    }
    #pragma unroll
    for (int j = 0; j < 4; ++j) {
        int b = b0 + 4 * j;
        R[((size_t)(b * H + h) * 64 + o) * 64 + x] = make_float2(rr[j], ri[j]);
    }
}

// ---------------------------------------------------------------------------
// irFFT, 4 rows per block.
// ---------------------------------------------------------------------------
__global__ __launch_bounds__(256) void k_irfft(const float2* __restrict__ R,
                                               float* __restrict__ out)
{
    __shared__ float2 Fsh[4][64];
    int rloc = threadIdx.x >> 6;
    int r    = threadIdx.x & 63;
    int bho  = blockIdx.x * 4 + rloc;
    int o  = bho & 63, bh = bho >> 6;
    int h  = bh & 7,   b  = bh >> 3;

    Fsh[threadIdx.x >> 6][threadIdx.x & 63] = R[(size_t)blockIdx.x * 256 + threadIdx.x];
    __syncthreads();

    float sr_, cr_;
    sincosf(3.0679615757712823e-3f * (float)r, &sr_, &cr_);
    float s32, c32;
    sincosf(9.8174770424681038e-2f * (float)r, &s32, &c32);

    float gr[32], gi[32];
    float wr = 1.f, wi = 0.f;
    #pragma unroll
    for (int f = 0; f < 32; ++f) {
        float2 Fa = Fsh[rloc][f];
        float2 Fb = Fsh[rloc][f + 32];
        float wbr = wr * c32 - wi * s32;
        float wbi = wr * s32 + wi * c32;
        gr[f] = wr * Fa.x - wi * Fa.y + wbr * Fb.x - wbi * Fb.y;
        gi[f] = wr * Fa.y + wi * Fa.x + wbr * Fb.y + wbi * Fb.x;
        float t = wr * cr_ - wi * sr_;
        wi = wr * sr_ + wi * cr_;
        wr = t;
    }
    gr[0] -= 0.5f * Fsh[rloc][0].x;

    const float scl = 2.384185791015625e-7f;   // 2/(4096*2048)
    float* dst = out + ((size_t)(b * E + o) * H + h) * L + r;
    #pragma unroll
    for (int i = 0; i < 16; ++i) {
        float ae = 0.f, ao = 0.f;
        #pragma unroll
        for (int f = 0; f < 32; f += 2) {
            ae = fmaf(gr[f],      CS32[(f * i) & 31],       ae);
            ae = fmaf(gi[f],     -SN32[(f * i) & 31],       ae);
            ao = fmaf(gr[f + 1],  CS32[((f + 1) * i) & 31], ao);
            ao = fmaf(gi[f + 1], -SN32[((f + 1) * i) & 31], ao);
        }
        dst[64 * i]        = scl * (ae + ao);
        dst[64 * (i + 16)] = scl * (ae - ao);
    }
}

// ---------------------------------------------------------------------------
extern "C" void kernel_launch(void* const* d_in, const int* in_sizes, int n_in,
                              void* d_out, int out_size, void* d_ws, size_t ws_size,
                              hipStream_t stream)
{
    (void)in_sizes; (void)n_in; (void)out_size; (void)ws_size;
    const float* q    = (const float*)d_in[0];
    const float* k    = (const float*)d_in[1];
    // d_in[2] = v, unused by the reference
    const float* w_re = (const float*)d_in[3];
    const float* w_im = (const float*)d_in[4];
    float* out = (float*)d_out;

    // d_out scratch (64 MiB, all dead before k_irfft overwrites):
    //   Xq [0,4M) Xk [4,8M) U [8,12M) Bg [12,13M) Wt [16,32M)
    float2*    Xq  = (float2*)d_out;
    float2*    Xk  = Xq + PLANE;
    float2*    Uu  = Xk + PLANE;
    _Float16*  Bhi = (_Float16*)((char*)d_out + (size_t)12 * 1024 * 1024);
    _Float16*  Blo = Bhi + 262144;
    float2*    Wt  = (float2*)((char*)d_out + (size_t)16 * 1024 * 1024);
    // d_ws: R (4 MB, survives into k_irfft)
    float2*    R   = (float2*)d_ws;

    k_dftmat<<<1024, 256, 0, stream>>>(Bhi, Blo);
    k_wtrans<<< 512, 256, 0, stream>>>(w_re, w_im, Wt);
    k_dftg  <<< 512, 256, 0, stream>>>(q, k, Bhi, Blo, (float*)Xq, (float*)Xk);
    k_mid   <<< 256, 256, 0, stream>>>(Xq, Xk, Uu);
    k_wmix  <<< 512, 256, 0, stream>>>(Uu, Wt, R);
    k_irfft <<<2048, 256, 0, stream>>>(R, out);
}

// Round 8
// 107.742 us; speedup vs baseline: 1.3507x; 1.3507x over previous
//
#include <hip/hip_runtime.h>
#include <math.h>

#define B 16
#define E 64
#define H 8
#define L 2048
#define M 64
#define PLANE (B*H*E*M)   // 524288 float2 per spectral plane

// exact 32-pt DFT twiddles: CS32[j]=cos(pi j/16), SN32[j]=sin(pi j/16)
constexpr float CS32[32] = {
     1.0f,                    0.9807852804032304f,   0.9238795325112868f,   0.8314696123025452f,
     0.7071067811865476f,     0.5555702330196022f,   0.3826834323650898f,   0.1950903220161283f,
     0.0f,                   -0.1950903220161283f,  -0.3826834323650898f,  -0.5555702330196022f,
    -0.7071067811865476f,    -0.8314696123025452f,  -0.9238795325112868f,  -0.9807852804032304f,
    -1.0f,                   -0.9807852804032304f,  -0.9238795325112868f,  -0.8314696123025452f,
    -0.7071067811865476f,    -0.5555702330196022f,  -0.3826834323650898f,  -0.1950903220161283f,
     0.0f,                    0.1950903220161283f,   0.3826834323650898f,   0.5555702330196022f,
     0.7071067811865476f,     0.8314696123025452f,   0.9238795325112868f,   0.9807852804032304f
};
constexpr float SN32[32] = {
     0.0f,                    0.1950903220161283f,   0.3826834323650898f,   0.5555702330196022f,
     0.7071067811865476f,     0.8314696123025452f,   0.9238795325112868f,   0.9807852804032304f,
     1.0f,                    0.9807852804032304f,   0.9238795325112868f,   0.8314696123025452f,
     0.7071067811865476f,     0.5555702330196022f,   0.3826834323650898f,   0.1950903220161283f,
     0.0f,                   -0.1950903220161283f,  -0.3826834323650898f,  -0.5555702330196022f,
    -0.7071067811865476f,    -0.8314696123025452f,  -0.9238795325112868f,  -0.9807852804032304f,
    -1.0f,                   -0.9807852804032304f,  -0.9238795325112868f,  -0.8314696123025452f,
    -0.7071067811865476f,    -0.5555702330196022f,  -0.3826834323650898f,  -0.1950903220161283f
};

__device__ inline void ctanhf_stable(float x, float y, float& re, float& im) {
    float ax = fabsf(x);
    if (ax > 11.0f) { re = copysignf(1.0f, x); im = 0.0f; return; }
    float t    = tanf(y);
    float beta = 1.0f + t * t;
    float s    = sinhf(x);
    float rho  = sqrtf(1.0f + s * s);
    float den  = 1.0f + beta * s * s;
    re = (beta * rho * s) / den;
    im = t / den;
}

// ---------------------------------------------------------------------------
// One-time tables: Tg[r*32+m] = e^{-i pi m r/1024} (r<32, m<32),
//                  Cg[j]      = e^{-i pi j/32}     (j<32).
// Symmetries used in k_dft:  T[r][m+32] = T[r][m]*Cg[r],
//                            T[r+32][m] = T[r][m]*Cg[m] (and *-Cg[m] for m+32).
// ---------------------------------------------------------------------------
__global__ __launch_bounds__(256) void k_twiddle(float2* __restrict__ T,
                                                 float2* __restrict__ C)
{
    int idx = blockIdx.x * 256 + threadIdx.x;
    if (idx < 1024) {
        int r = idx >> 5, m = idx & 31;
        double a = -3.14159265358979323846 * (double)(m * r) / 1024.0;
        T[idx] = make_float2((float)cos(a), (float)sin(a));
    } else if (idx < 1056) {
        int j = idx - 1024;
        double a = -3.14159265358979323846 * (double)j / 32.0;
        C[j] = make_float2((float)cos(a), (float)sin(a));
    }
}

// ---------------------------------------------------------------------------
// W transpose: w_re/w_im [H][E][O][M] -> Wt float2 [H][m][E][O].
// ---------------------------------------------------------------------------
__global__ __launch_bounds__(256) void k_wtrans(const float* __restrict__ wre,
                                                const float* __restrict__ wim,
                                                float2* __restrict__ Wt)
{
    __shared__ float tre[64][65], tim[64][65];
    int h  = blockIdx.x >> 6, rt = blockIdx.x & 63;
    int tid = threadIdx.x;

    int x = tid & 63, r4 = tid >> 6;
    const size_t base = ((size_t)h * 4096 + (size_t)rt * 64) * 64;
    #pragma unroll
    for (int j = 0; j < 16; ++j) {
        int row = j * 4 + r4;
        tre[row][x] = wre[base + (size_t)row * 64 + x];
        tim[row][x] = wim[base + (size_t)row * 64 + x];
    }
    __syncthreads();

    int row = tid & 63, x4 = tid >> 6;
    #pragma unroll
    for (int j = 0; j < 16; ++j) {
        int xx = j * 4 + x4;
        Wt[((size_t)h * 64 + xx) * 4096 + (size_t)rt * 64 + row] =
            make_float2(tre[row][xx], tim[row][xx]);
    }
}

// ---------------------------------------------------------------------------
// Forward DFT, 4 rows per block, all phase-2 operands in LDS (45.3 KB -> 3/CU).
// Phase 1: thread (row, r=lane): Y_r[f] = 32-pt real DFT of x[64i+r], f<=16.
// Phase 2: thread (row, half, mlow): partial sums for X[mlow], X[mlow+32]
//          over its r-half using the 32x32 quarter twiddle table + Cg factors;
//          half-1 post-multiplies by +-Cg[mlow]; halves combine via Psc.
// ---------------------------------------------------------------------------
__global__ __launch_bounds__(256) void k_dft(const float* __restrict__ q,
                                             const float* __restrict__ k,
                                             const float2* __restrict__ Tg,
                                             const float2* __restrict__ Cgl,
                                             float2* __restrict__ Xq,
                                             float2* __restrict__ Xk)
{
    __shared__ float2 Ysh[4][64][17];   // 34,816 B
    __shared__ float2 Tsm[32][32];      //  8,192 B
    __shared__ float2 Cgs[32];          //    256 B
    __shared__ float4 Psc[4][32];       //  2,048 B  (total 45,312 B)

    int tid  = threadIdx.x;
    int rloc = tid >> 6;
    int lane = tid & 63;
    int rid  = blockIdx.x * 4 + rloc;                  // 0..16383
    int tensor = rid >> 13;
    int r8 = rid & 8191;
    int b = r8 >> 9, h = (r8 >> 6) & 7, e = r8 & 63;

    // stage twiddle tables (8.25 KB, L2-resident)
    #pragma unroll
    for (int j = 0; j < 4; ++j) ((float2*)Tsm)[tid + 256 * j] = Tg[tid + 256 * j];
    if (tid < 32) Cgs[tid] = Cgl[tid];

    const float* src = (tensor ? k : q) + (((size_t)(b * E + e) * H + h) * L) + lane;
    float xs[32];
    #pragma unroll
    for (int i = 0; i < 32; ++i) xs[i] = src[i * 64];

    float s_[16], d_[16];
    #pragma unroll
    for (int i = 1; i <= 15; ++i) { s_[i] = xs[i] + xs[32 - i]; d_[i] = xs[i] - xs[32 - i]; }

    #pragma unroll
    for (int f = 0; f <= 16; ++f) {
        float ar = xs[0] + ((f & 1) ? -xs[16] : xs[16]);
        float ai = 0.f;
        #pragma unroll
        for (int i = 1; i <= 15; ++i) {
            ar = fmaf(s_[i], CS32[(f * i) & 31], ar);
            ai = fmaf(d_[i], SN32[(f * i) & 31], ai);
        }
        Ysh[rloc][lane][f] = make_float2(ar, -ai);
    }
    __syncthreads();

    // phase 2: thread = (row, half, mlow)
    int mlow = tid & 31;
    int half = (tid >> 5) & 1;
    int row  = tid >> 6;
    int fi   = (mlow <= 16) ? mlow : 32 - mlow;
    float sgn = (mlow <= 16) ? 1.f : -1.f;

    float ar0 = 0.f, ai0 = 0.f, ar1 = 0.f, ai1 = 0.f;
    int rbase = half * 32;
    #pragma unroll
    for (int rb = 0; rb < 4; ++rb) {
        float2 tb[8], cb[8], yb[8];
        #pragma unroll
        for (int j = 0; j < 8; ++j) {
            int rp = rb * 8 + j;
            tb[j] = Tsm[rp][mlow];
            cb[j] = Cgs[rp];
            yb[j] = Ysh[row][rbase + rp][fi];
        }
        #pragma unroll
        for (int j = 0; j < 8; ++j) {
            float yr = yb[j].x, yi = sgn * yb[j].y;
            ar0 = fmaf(yr, tb[j].x, ar0); ar0 = fmaf(-yi, tb[j].y, ar0);
            ai0 = fmaf(yr, tb[j].y, ai0); ai0 = fmaf(yi, tb[j].x, ai0);
            float t2r = tb[j].x * cb[j].x - tb[j].y * cb[j].y;
            float t2i = tb[j].x * cb[j].y + tb[j].y * cb[j].x;
            ar1 = fmaf(yr, t2r, ar1); ar1 = fmaf(-yi, t2i, ar1);
            ai1 = fmaf(yr, t2i, ai1); ai1 = fmaf(yi, t2r, ai1);
        }
    }

    if (half) {
        // multiply half-1 partials by Cg[mlow] (m) and -Cg[mlow] (m+32)
        float2 dchk = Cgs[mlow];
        float t;
        t   = ar0 * dchk.x - ai0 * dchk.y;
        ai0 = ar0 * dchk.y + ai0 * dchk.x;  ar0 = t;
        t   = ar1 * dchk.x - ai1 * dchk.y;
        ai1 = ar1 * dchk.y + ai1 * dchk.x;  ar1 = t;
        ar1 = -ar1; ai1 = -ai1;
        Psc[row][mlow] = make_float4(ar0, ai0, ar1, ai1);
    }
    __syncthreads();
    if (!half) {
        float4 p = Psc[row][mlow];
        float2* dst = (tensor ? Xk : Xq) + ((size_t)(b * H + h) * E + e) * M;
        dst[mlow]      = make_float2(ar0 + p.x, ai0 + p.y);
        dst[mlow + 32] = make_float2(ar1 + p.z, ai1 + p.w);
    }
}

// ---------------------------------------------------------------------------
// Per (bh, x-half): S = tanh(Q^T K) (fp32 accum), then
// U[h][x][b][e] = sum_y S[x][y] K[e][y]
// ---------------------------------------------------------------------------
__global__ __launch_bounds__(256) void k_mid(const float2* __restrict__ Xq,
                                             const float2* __restrict__ Xk,
                                             float2* __restrict__ U)
{
    __shared__ float Qre[64][32], Qim[64][32];   // [e][xl]; becomes S [y][xl]
    __shared__ float Kre[64][65], Kim[64][65];   // [e][m], padded

    int bh = blockIdx.x >> 1;
    int xh = (blockIdx.x & 1) * 32;
    int b  = bh >> 3, h = bh & 7;
    int tid = threadIdx.x;
    const float2* xq = Xq + (size_t)bh * 4096;
    const float2* xk = Xk + (size_t)bh * 4096;

    #pragma unroll
    for (int j = 0; j < 8; ++j) {
        int idx = tid + 256 * j;
        int e = idx >> 5, xl = idx & 31;
        float2 v = xq[(e << 6) + xh + xl];
        Qre[e][xl] = v.x; Qim[e][xl] = v.y;
    }
    #pragma unroll
    for (int j = 0; j < 16; ++j) {
        int idx = tid + 256 * j;
        int e = idx >> 6, mm = idx & 63;
        float2 v = xk[idx];
        Kre[e][mm] = v.x; Kim[e][mm] = v.y;
    }
    __syncthreads();

    int x  = tid & 31;
    int y0 = (tid >> 5) * 8;
    float ar[8], ai[8];
    #pragma unroll
    for (int j = 0; j < 8; ++j) { ar[j] = 0.f; ai[j] = 0.f; }

    for (int e = 0; e < 64; ++e) {
        float qr = Qre[e][x], qi = Qim[e][x];
        #pragma unroll
        for (int j = 0; j < 8; ++j) {
            float kr = Kre[e][y0 + j], ki = Kim[e][y0 + j];
            ar[j] = fmaf(qr, kr, ar[j]); ar[j] = fmaf(-qi, ki, ar[j]);
            ai[j] = fmaf(qr, ki, ai[j]); ai[j] = fmaf( qi, kr, ai[j]);
        }
    }
    float trj[8], tij[8];
    #pragma unroll
    for (int j = 0; j < 8; ++j) ctanhf_stable(ar[j], ai[j], trj[j], tij[j]);

    __syncthreads();
    #pragma unroll
    for (int j = 0; j < 8; ++j) { Qre[y0 + j][x] = trj[j]; Qim[y0 + j][x] = tij[j]; }
    __syncthreads();

    int eL  = tid & 63;
    int xq4 = tid >> 6;
    float ur[8], ui[8];
    #pragma unroll
    for (int j = 0; j < 8; ++j) { ur[j] = 0.f; ui[j] = 0.f; }

    for (int y = 0; y < 64; ++y) {
        float kr = Kre[eL][y], ki = Kim[eL][y];
        #pragma unroll
        for (int xp = 0; xp < 8; ++xp) {
            int xx = xp * 4 + xq4;
            float sr = Qre[y][xx], si = Qim[y][xx];
            ur[xp] += sr * kr - si * ki;
            ui[xp] += sr * ki + si * kr;
        }
    }
    #pragma unroll
    for (int xp = 0; xp < 8; ++xp) {
        int xx = xp * 4 + xq4;
        U[(((size_t)h * 64 + xh + xx) * 16 + b) * 64 + eL] = make_float2(ur[xp], ui[xp]);
    }
}

// ---------------------------------------------------------------------------
// Per (h, mode x): R[b][o] = sum_e U[b][e] * Wt[e][o]
// ---------------------------------------------------------------------------
__global__ __launch_bounds__(256) void k_wmix(const float2* __restrict__ U,   // [h][x][b][e]
                                              const float2* __restrict__ Wt,  // [h][x][e][o]
                                              float2* __restrict__ R)
{
    __shared__ float2 Usm[16][64];
    __shared__ float2 Wsm[64][64];

    int h = blockIdx.x >> 6, x = blockIdx.x & 63;
    int tid = threadIdx.x;

    const float2* usrc = U  + ((size_t)h * 64 + x) * 1024;
    #pragma unroll
    for (int j = 0; j < 4; ++j) {
        int idx = tid + 256 * j;
        ((float2*)Usm)[idx] = usrc[idx];
    }
    const float2* wsrc = Wt + ((size_t)h * 64 + x) * 4096;
    #pragma unroll
    for (int j = 0; j < 16; ++j) {
        int idx = tid + 256 * j;
        ((float2*)Wsm)[idx] = wsrc[idx];
    }
    __syncthreads();

    int o = tid & 63, b0 = tid >> 6;
    float rr[4], ri[4];
    #pragma unroll
    for (int j = 0; j < 4; ++j) { rr[j] = 0.f; ri[j] = 0.f; }

    for (int e = 0; e < 64; ++e) {
        float2 w = Wsm[e][o];
        #pragma unroll
        for (int j = 0; j < 4; ++j) {
            float2 u = Usm[b0 + 4 * j][e];
            rr[j] += u.x * w.x - u.y * w.y;
            ri[j] += u.x * w.y + u.y * w.x;
        }
    }
    #pragma unroll
    for (int j = 0; j < 4; ++j) {
        int b = b0 + 4 * j;
        R[((size_t)(b * H + h) * 64 + o) * 64 + x] = make_float2(rr[j], ri[j]);
    }
}

// ---------------------------------------------------------------------------
// irFFT, 4 rows per block.
// ---------------------------------------------------------------------------
__global__ __launch_bounds__(256) void k_irfft(const float2* __restrict__ R,
                                               float* __restrict__ out)
{
    __shared__ float2 Fsh[4][64];
    int rloc = threadIdx.x >> 6;
    int r    = threadIdx.x & 63;
    int bho  = blockIdx.x * 4 + rloc;
    int o  = bho & 63, bh = bho >> 6;
    int h  = bh & 7,   b  = bh >> 3;

    Fsh[threadIdx.x >> 6][threadIdx.x & 63] = R[(size_t)blockIdx.x * 256 + threadIdx.x];
    __syncthreads();

    float sr_, cr_;
    sincosf(3.0679615757712823e-3f * (float)r, &sr_, &cr_);
    float s32, c32;
    sincosf(9.8174770424681038e-2f * (float)r, &s32, &c32);

    float gr[32], gi[32];
    float wr = 1.f, wi = 0.f;
    #pragma unroll
    for (int f = 0; f < 32; ++f) {
        float2 Fa = Fsh[rloc][f];
        float2 Fb = Fsh[rloc][f + 32];
        float wbr = wr * c32 - wi * s32;
        float wbi = wr * s32 + wi * c32;
        gr[f] = wr * Fa.x - wi * Fa.y + wbr * Fb.x - wbi * Fb.y;
        gi[f] = wr * Fa.y + wi * Fa.x + wbr * Fb.y + wbi * Fb.x;
        float t = wr * cr_ - wi * sr_;
        wi = wr * sr_ + wi * cr_;
        wr = t;
    }
    gr[0] -= 0.5f * Fsh[rloc][0].x;

    const float scl = 2.384185791015625e-7f;   // 2/(4096*2048)
    float* dst = out + ((size_t)(b * E + o) * H + h) * L + r;
    #pragma unroll
    for (int i = 0; i < 16; ++i) {
        float ae = 0.f, ao = 0.f;
        #pragma unroll
        for (int f = 0; f < 32; f += 2) {
            ae = fmaf(gr[f],      CS32[(f * i) & 31],       ae);
            ae = fmaf(gi[f],     -SN32[(f * i) & 31],       ae);
            ao = fmaf(gr[f + 1],  CS32[((f + 1) * i) & 31], ao);
            ao = fmaf(gi[f + 1], -SN32[((f + 1) * i) & 31], ao);
        }
        dst[64 * i]        = scl * (ae + ao);
        dst[64 * (i + 16)] = scl * (ae - ao);
    }
}

// ---------------------------------------------------------------------------
extern "C" void kernel_launch(void* const* d_in, const int* in_sizes, int n_in,
                              void* d_out, int out_size, void* d_ws, size_t ws_size,
                              hipStream_t stream)
{
    (void)in_sizes; (void)n_in; (void)out_size; (void)ws_size;
    const float* q    = (const float*)d_in[0];
    const float* k    = (const float*)d_in[1];
    // d_in[2] = v, unused by the reference
    const float* w_re = (const float*)d_in[3];
    const float* w_im = (const float*)d_in[4];
    float* out = (float*)d_out;

    // d_out scratch (dead before k_irfft): Xq [0,4M) Xk [4,8M) U [8,12M) Wt [16,32M)
    float2* Xq = (float2*)d_out;
    float2* Xk = Xq + PLANE;
    float2* Uu = Xk + PLANE;
    float2* Wt = (float2*)((char*)d_out + (size_t)16 * 1024 * 1024);
    // d_ws: R (4MB, survives) + Tg (8KB) + Cg (256B)
    float2* R  = (float2*)d_ws;
    float2* Tg = R + (size_t)PLANE;
    float2* Cg = Tg + 1024;

    k_twiddle<<<   5, 256, 0, stream>>>(Tg, Cg);
    k_wtrans <<< 512, 256, 0, stream>>>(w_re, w_im, Wt);
    k_dft    <<<4096, 256, 0, stream>>>(q, k, Tg, Cg, Xq, Xk);
    k_mid    <<< 256, 256, 0, stream>>>(Xq, Xk, Uu);
    k_wmix   <<< 512, 256, 0, stream>>>(Uu, Wt, R);
    k_irfft  <<<2048, 256, 0, stream>>>(R, out);
}